// Round 5
// baseline (4515.598 us; speedup 1.0000x reference)
//
#include <hip/hip_runtime.h>

namespace {
constexpr int kH = 512, kD = 256, kO = 256, kB = 32, kT = 2048;
constexpr int kRows = kB * kT;  // 65536
}

// ---------------- prep: W (transposed), W_in^T, W_out^T ----------------
__global__ __launch_bounds__(256) void prep_kernel(
    const float* __restrict__ S, const float* __restrict__ A,
    const float* __restrict__ lam_raw, const float* __restrict__ W_in,
    const float* __restrict__ W_out, float* __restrict__ Wt,
    float* __restrict__ W_in_t, float* __restrict__ Wout_t) {
  const int idx = blockIdx.x * 256 + threadIdx.x;
  const float lam = 1.0f / (1.0f + __expf(-lam_raw[0]));
  if (idx < kH * kH) {
    // Wt[k][j] = W[j][k]; W = lam*0.5*(S+S^T) + (1-lam)*0.5*(A-A^T)
    const int k = idx >> 9, j = idx & (kH - 1);
    const float sym = 0.5f * (S[j * kH + k] + S[k * kH + j]);
    const float asym = 0.5f * (A[j * kH + k] - A[k * kH + j]);
    Wt[idx] = lam * sym + (1.0f - lam) * asym;
  }
  if (idx < kD * kH) {  // W_in_t[d][h] = W_in[h][d]
    const int d = idx >> 9, h = idx & (kH - 1);
    W_in_t[idx] = W_in[h * kD + d];
  }
  if (idx < kH * kO) {  // Wout_t[h][o] = W_out[o][h]
    const int h = idx >> 8, o = idx & (kO - 1);
    Wout_t[idx] = W_out[o * kH + h];
  }
}

// ---------------- fp32 tiled GEMM: C[M][N] = A[M][K] @ Bt[K][N] + bias ----------------
template <int BM, int BN, int BK>
__global__ __launch_bounds__(256) void gemm_bias_kernel(
    const float* __restrict__ A, const float* __restrict__ Bt,
    const float* __restrict__ bias, float* __restrict__ C,
    int M, int N, int K) {
  __shared__ float As[BK][BM + 4];
  __shared__ float Bs[BK][BN];
  const int tid = threadIdx.x;
  const int m0 = blockIdx.x * BM, n0 = blockIdx.y * BN;
  const int ar = tid >> 2, ac = (tid & 3) << 2;
  const int br = tid >> 4, bc = (tid & 15) << 2;
  const int tx = tid & 15, ty = tid >> 4;
  float4 acc[8];
#pragma unroll
  for (int i = 0; i < 8; ++i) acc[i] = make_float4(0.f, 0.f, 0.f, 0.f);

  for (int k0 = 0; k0 < K; k0 += BK) {
    const float4 a0 = *(const float4*)&A[(long)(m0 + ar) * K + k0 + ac];
    const float4 a1 = *(const float4*)&A[(long)(m0 + ar + 64) * K + k0 + ac];
    const float4 b0 = *(const float4*)&Bt[(long)(k0 + br) * N + n0 + bc];
    __syncthreads();
    As[ac + 0][ar] = a0.x; As[ac + 1][ar] = a0.y;
    As[ac + 2][ar] = a0.z; As[ac + 3][ar] = a0.w;
    As[ac + 0][ar + 64] = a1.x; As[ac + 1][ar + 64] = a1.y;
    As[ac + 2][ar + 64] = a1.z; As[ac + 3][ar + 64] = a1.w;
    *(float4*)&Bs[br][bc] = b0;
    __syncthreads();
#pragma unroll
    for (int kk = 0; kk < BK; ++kk) {
      const float4 b4 = *(const float4*)&Bs[kk][tx * 4];
      const float4 va0 = *(const float4*)&As[kk][ty * 8];
      const float4 va1 = *(const float4*)&As[kk][ty * 8 + 4];
#define FMA_ROW(ACC, SV)                                                   \
      ACC.x += (SV) * b4.x; ACC.y += (SV) * b4.y;                          \
      ACC.z += (SV) * b4.z; ACC.w += (SV) * b4.w;
      FMA_ROW(acc[0], va0.x) FMA_ROW(acc[1], va0.y)
      FMA_ROW(acc[2], va0.z) FMA_ROW(acc[3], va0.w)
      FMA_ROW(acc[4], va1.x) FMA_ROW(acc[5], va1.y)
      FMA_ROW(acc[6], va1.z) FMA_ROW(acc[7], va1.w)
#undef FMA_ROW
    }
  }
  const float4 bv = *(const float4*)&bias[n0 + tx * 4];
#pragma unroll
  for (int mi = 0; mi < 8; ++mi) {
    float4 r;
    r.x = acc[mi].x + bv.x; r.y = acc[mi].y + bv.y;
    r.z = acc[mi].z + bv.z; r.w = acc[mi].w + bv.w;
    *(float4*)&C[(long)(m0 + ty * 8 + mi) * N + n0 + tx * 4] = r;
  }
}

// fast tanh: clamp + exp-based; |err| ~1e-7 rel, safe (no inf/NaN after clamp)
__device__ __forceinline__ float fast_tanh(float x) {
  x = fminf(fmaxf(x, -10.0f), 10.0f);
  const float e = __expf(2.0f * x);
  return (e - 1.0f) / (e + 1.0f);
}

// ---------------- recurrence: 2 batches per block, W registers shared ----------------
// Block (g, s): slice s (outputs [64s,64s+64)) of batches bA=g and bB=g+16.
// 512 threads = 8 waves; wave kc owns k-chunk [64kc,64kc+64); lane j -> output 64s+j.
// Agent-scope tagged-word exchange (round-2-proven): word = (seq<<32)|h_bits,
// double-buffered by step parity. Per sub-step: poll -> B1 -> partial -> B2 ->
// wave0 finalize+publish. B1 also orders this block's part[] reads (wave0, step t)
// before any sibling wave's part[] writes (step t+1) via wave0's program order.
// While pipeline A's publish travels the L3 round trip, the block computes B.
__global__ __launch_bounds__(512, 1) void rnn_kernel(
    const float* __restrict__ Wt, const float* __restrict__ h0,
    float* __restrict__ hs, unsigned long long* __restrict__ exch) {
  const int bid = blockIdx.x;
  const int g = bid & 15;   // batch-pair group
  const int s = bid >> 4;   // slice 0..7
  const int bA = g, bB = g + 16;
  const int tid = threadIdx.x;
  const int j = tid & 63;
  const int kc = tid >> 6;
  const int jg = s * 64 + j;

  __shared__ float hA[kH], hB[kH];        // per-wave-private 64-chunks
  __shared__ float pA[8 * 64], pB[8 * 64];

  // W slice into registers (shared by both batches): wk[m] = W[jg][64*kc+m]
  float wk[64];
  const float* wp = Wt + (long)(64 * kc) * kH + jg;
#pragma unroll
  for (int m = 0; m < 64; ++m) wk[m] = wp[(long)m * kH];

  float* hbA = hs + (long)bA * kT * kH;   // pre-filled with xp rows
  float* hbB = hs + (long)bB * kT * kH;
  unsigned long long* hgA = exch + (long)bA * 1024;  // [2 slots][512]
  unsigned long long* hgB = exch + (long)bB * 1024;

  hA[tid] = h0[bA * kH + tid];
  hB[tid] = h0[bB * kH + tid];
  float xpA = 0.f, xpB = 0.f;
  if (kc == 0) { xpA = hbA[jg]; xpB = hbB[jg]; }
  __syncthreads();

  for (int t = 0; t < kT; ++t) {
    // ================= pipeline A =================
    if (t > 0) {
      unsigned long long* p = &hgA[(t & 1) * 512 + tid];
      unsigned long long v;
      do {
        v = __hip_atomic_load(p, __ATOMIC_RELAXED, __HIP_MEMORY_SCOPE_AGENT);
      } while ((unsigned)(v >> 32) != (unsigned)t);
      hA[tid] = __uint_as_float((unsigned)v);
    }
    __syncthreads();  // B1a
    {
      const float4* h4 = (const float4*)&hA[64 * kc];
      float a0 = 0.f, a1 = 0.f, a2 = 0.f, a3 = 0.f;
#pragma unroll
      for (int q = 0; q < 16; ++q) {
        const float4 hv = h4[q];
        a0 += wk[4 * q + 0] * hv.x;
        a1 += wk[4 * q + 1] * hv.y;
        a2 += wk[4 * q + 2] * hv.z;
        a3 += wk[4 * q + 3] * hv.w;
      }
      pA[kc * 64 + j] = (a0 + a1) + (a2 + a3);
    }
    __syncthreads();  // B2a
    if (kc == 0) {
      float sum = xpA;
#pragma unroll
      for (int e = 0; e < 8; ++e) sum += pA[e * 64 + j];
      const float hn = fast_tanh(sum);
      hbA[(long)t * kH + jg] = hn;
      __hip_atomic_store(&hgA[((t + 1) & 1) * 512 + jg],
                         ((unsigned long long)(unsigned)(t + 1) << 32) |
                             __float_as_uint(hn),
                         __ATOMIC_RELAXED, __HIP_MEMORY_SCOPE_AGENT);
      xpA = (t + 1 < kT) ? hbA[(long)(t + 1) * kH + jg] : 0.f;
    }
    // ================= pipeline B =================
    if (t > 0) {
      unsigned long long* p = &hgB[(t & 1) * 512 + tid];
      unsigned long long v;
      do {
        v = __hip_atomic_load(p, __ATOMIC_RELAXED, __HIP_MEMORY_SCOPE_AGENT);
      } while ((unsigned)(v >> 32) != (unsigned)t);
      hB[tid] = __uint_as_float((unsigned)v);
    }
    __syncthreads();  // B1b
    {
      const float4* h4 = (const float4*)&hB[64 * kc];
      float a0 = 0.f, a1 = 0.f, a2 = 0.f, a3 = 0.f;
#pragma unroll
      for (int q = 0; q < 16; ++q) {
        const float4 hv = h4[q];
        a0 += wk[4 * q + 0] * hv.x;
        a1 += wk[4 * q + 1] * hv.y;
        a2 += wk[4 * q + 2] * hv.z;
        a3 += wk[4 * q + 3] * hv.w;
      }
      pB[kc * 64 + j] = (a0 + a1) + (a2 + a3);
    }
    __syncthreads();  // B2b
    if (kc == 0) {
      float sum = xpB;
#pragma unroll
      for (int e = 0; e < 8; ++e) sum += pB[e * 64 + j];
      const float hn = fast_tanh(sum);
      hbB[(long)t * kH + jg] = hn;
      __hip_atomic_store(&hgB[((t + 1) & 1) * 512 + jg],
                         ((unsigned long long)(unsigned)(t + 1) << 32) |
                             __float_as_uint(hn),
                         __ATOMIC_RELAXED, __HIP_MEMORY_SCOPE_AGENT);
      xpB = (t + 1 < kT) ? hbB[(long)(t + 1) * kH + jg] : 0.f;
    }
  }
}

// ---------------- in-place row softmax (rows of 256), one wave per row ----------------
__global__ __launch_bounds__(256) void softmax_kernel(float* __restrict__ Z) {
  const int lane = threadIdx.x & 63;
  const int wid = threadIdx.x >> 6;
  const long row = (long)blockIdx.x * 4 + wid;
  float* z = Z + row * kO;
  float4 v = *(float4*)&z[lane * 4];
  float m = fmaxf(fmaxf(v.x, v.y), fmaxf(v.z, v.w));
#pragma unroll
  for (int off = 32; off > 0; off >>= 1) m = fmaxf(m, __shfl_xor(m, off));
  v.x = __expf(v.x - m); v.y = __expf(v.y - m);
  v.z = __expf(v.z - m); v.w = __expf(v.w - m);
  float ssum = v.x + v.y + v.z + v.w;
#pragma unroll
  for (int off = 32; off > 0; off >>= 1) ssum += __shfl_xor(ssum, off);
  const float r = 1.0f / ssum;
  v.x *= r; v.y *= r; v.z *= r; v.w *= r;
  *(float4*)&z[lane * 4] = v;
}

extern "C" void kernel_launch(void* const* d_in, const int* in_sizes, int n_in,
                              void* d_out, int out_size, void* d_ws, size_t ws_size,
                              hipStream_t stream) {
  const float* x     = (const float*)d_in[0];
  const float* h0    = (const float*)d_in[1];
  const float* S     = (const float*)d_in[2];
  const float* A     = (const float*)d_in[3];
  const float* lam   = (const float*)d_in[4];
  const float* W_in  = (const float*)d_in[5];
  const float* b_in  = (const float*)d_in[6];
  const float* W_out = (const float*)d_in[7];
  const float* b_out = (const float*)d_in[8];

  float* ys = (float*)d_out;                  // [B,T,O]
  float* hs = ys + (long)kB * kT * kO;        // [B,T,H] — doubles as xp scratch

  float* Wt     = (float*)d_ws;               // 1MB
  float* W_in_t = Wt + kH * kH;               // 512KB, dead after gemm1
  float* Wout_t = W_in_t + kD * kH;           // 512KB (total ws = 2MB)

  // exch (256KB) aliases the dead W_in_t region (read only by gemm1, stream-
  // ordered before rnn_kernel). Leftover float bit patterns in the tag word
  // can't equal a live seq tag 1..2048 (those are denormal patterns), nor can
  // 0xAA poison.
  unsigned long long* exch = (unsigned long long*)W_in_t;

  prep_kernel<<<1024, 256, 0, stream>>>(S, A, lam, W_in, W_out, Wt, W_in_t, Wout_t);

  // xp = x @ W_in^T + b_in  -> into hs region
  dim3 g2(kRows / 128, kH / 64);
  gemm_bias_kernel<128, 64, 16><<<g2, 256, 0, stream>>>(x, W_in_t, b_in, hs,
                                                        kRows, kH, kD);
  // scan: 128 blocks = 8 slices x 16 batch-pairs; 2 interleaved recurrences/block
  rnn_kernel<<<128, 512, 0, stream>>>(Wt, h0, hs, exch);

  // logits = hs @ W_out^T + b_out -> into ys region
  dim3 g4(kRows / 128, kO / 64);
  gemm_bias_kernel<128, 64, 16><<<g4, 256, 0, stream>>>(hs, Wout_t, b_out, ys,
                                                        kRows, kO, kH);
  // softmax in place
  softmax_kernel<<<kRows / 4, 256, 0, stream>>>(ys);
}